// Round 3
// baseline (1572.229 us; speedup 1.0000x reference)
//
#include <hip/hip_runtime.h>

// ROIBBoxHead: out = relu(relu(X@W1+b1)@W2+b2)@W3+b3
// X=[4096,12544] fp32, W1=[12544,1024], W2=[1024,1024], W3=[1024,324].
// Split-bf16 emulated-fp32 GEMM on the MFMA pipe:
//   a*b ~= ah*bh + ah*bl + al*bh   (error ~2^-16 relative)
// 128x128 tile, 4 waves, mfma_f32_16x16x32_bf16, XOR-swizzled LDS.
// R3: BKT templated (32/64). If workspace permits: GEMM1 at BK=32 with
// split-K=4 -> 32KB LDS/block -> 4 resident blocks/CU (16 waves). Fallback
// is the exact R2 config. GEMM2 now split-K=2 with fused reduce epilogue.

typedef __attribute__((ext_vector_type(4)))  float          f32x4;
typedef __attribute__((ext_vector_type(8)))  short          short8;
typedef __attribute__((ext_vector_type(4)))  unsigned int   uint4v;
typedef __attribute__((ext_vector_type(4)))  unsigned short ushort4v;
typedef __attribute__((ext_vector_type(8)))  unsigned short ushort8v;

#define BM 128
#define BN 128

// Truncation split: x ~= hi + lo, |x - hi - lo| <= 2^-16 |x|.
__device__ __forceinline__ void split_f32(float x, unsigned short& h, unsigned short& l) {
    unsigned int u = __float_as_uint(x);
    h = (unsigned short)(u >> 16);
    float hf = __uint_as_float(u & 0xFFFF0000u);
    l = (unsigned short)(__float_as_uint(x - hf) >> 16);
}

// ---------------------------------------------------------------------------
// Weight conversion: W[K][N] fp32 -> WhT[Npad][K], WlT[Npad][K] bf16 planes.
// 64x64 LDS transpose tile; vectorized ushort8 stores along K.
// grid = (Npad/64, K/64), block = 256.
// ---------------------------------------------------------------------------
__global__ __launch_bounds__(256) void convert_w_t(const float* __restrict__ W,
                                                   unsigned short* __restrict__ WhT,
                                                   unsigned short* __restrict__ WlT,
                                                   int K, int N) {
    __shared__ float tile[64][65];
    const int k0 = blockIdx.y * 64;
    const int n0 = blockIdx.x * 64;
    const int tid = threadIdx.x;
    const int kr = tid >> 4;          // 0..15
    const int nc = (tid & 15) * 4;    // 0..60
#pragma unroll
    for (int i = 0; i < 4; ++i) {
        const int k = kr + 16 * i;
        f32x4 v = (f32x4){0.f, 0.f, 0.f, 0.f};
        if (n0 + nc < N) v = *(const f32x4*)(W + (size_t)(k0 + k) * N + n0 + nc);
        tile[k][nc + 0] = v[0];
        tile[k][nc + 1] = v[1];
        tile[k][nc + 2] = v[2];
        tile[k][nc + 3] = v[3];
    }
    __syncthreads();
    const int nr = tid >> 2;          // 0..63
    const int kc = (tid & 3) * 16;    // 0..48
    ushort8v h0, h1, l0, l1;
#pragma unroll
    for (int j = 0; j < 8; ++j) {
        unsigned short hh, ll;
        split_f32(tile[kc + j][nr], hh, ll);
        h0[j] = hh; l0[j] = ll;
        split_f32(tile[kc + 8 + j][nr], hh, ll);
        h1[j] = hh; l1[j] = ll;
    }
    const size_t o = (size_t)(n0 + nr) * K + k0 + kc;
    *(ushort8v*)(WhT + o)     = h0;
    *(ushort8v*)(WhT + o + 8) = h1;
    *(ushort8v*)(WlT + o)     = l0;
    *(ushort8v*)(WlT + o + 8) = l1;
}

// ---------------------------------------------------------------------------
// Split-bf16 GEMM: C = A @ B (K-slice per blockIdx.z), BKT in {32,64}.
//   A_F32: A fp32, converted hi/lo during staging; else A given as planes.
//   EPI=0: +bias, relu, write bf16 hi/lo planes (stride ldC)
//   EPI=1: raw fp32 partial to Cf + z*gridDim.x*BM*ldC (N padded, no guard)
// Swizzle: chunk ^= (row & (CHUNKS-1)); <=2-way bank aliasing (free).
// ---------------------------------------------------------------------------
template<bool A_F32, int EPI, int BKT>
__global__ __launch_bounds__(256, BKT == 32 ? 4 : 2)
void gemm3split(const float* __restrict__ A32,
                const unsigned short* __restrict__ Ah,
                const unsigned short* __restrict__ Al,
                const unsigned short* __restrict__ BhT,
                const unsigned short* __restrict__ BlT,
                const float* __restrict__ bias,
                unsigned short* __restrict__ Ch,
                unsigned short* __restrict__ Cl,
                float* __restrict__ Cf,
                int K, int ktiles, int ldC) {
    constexpr int CHUNKS = BKT / 8;     // b128 chunks per row
    constexpr int XM     = CHUNKS - 1;  // swizzle mask
    constexpr int F4     = BKT / 4;     // f32x4 chunks per row (A_F32)
    constexpr int AROWS  = 256 / F4;    // rows per staging pass (A_F32)
    constexpr int AIT    = BM / AROWS;
    constexpr int BROWS  = 256 / CHUNKS;
    constexpr int BIT    = BM / BROWS;

    const int tid  = threadIdx.x;
    const int lane = tid & 63;
    const int wave = tid >> 6;
    const int kgrp = lane >> 4;
    const int m0 = blockIdx.x * BM;
    const int n0 = blockIdx.y * BN;
    const int kt_base = blockIdx.z * ktiles;
    const int wm = (wave >> 1) * 64;
    const int wn = (wave & 1) * 64;

    __shared__ __align__(16) unsigned short sAh[BM * BKT];
    __shared__ __align__(16) unsigned short sAl[BM * BKT];
    __shared__ __align__(16) unsigned short sBh[BN * BKT];
    __shared__ __align__(16) unsigned short sBl[BN * BKT];

    f32x4 acc[4][4];
#pragma unroll
    for (int m = 0; m < 4; ++m)
#pragma unroll
        for (int n = 0; n < 4; ++n) acc[m][n] = (f32x4){0.f, 0.f, 0.f, 0.f};

    const int arow   = tid / F4;       // A_F32 staging coords
    const int acol4  = tid % F4;
    const int brow   = tid / CHUNKS;   // bf16-plane staging coords
    const int bchunk = tid % CHUNKS;

    f32x4  aF[AIT];
    uint4v aH[BIT], aL[BIT];
    uint4v bH[BIT], bL[BIT];

    auto load_tile = [&](int kt) {
        const int k0 = (kt_base + kt) * BKT;
        if constexpr (A_F32) {
#pragma unroll
            for (int i = 0; i < AIT; ++i)
                aF[i] = *(const f32x4*)(A32 + (size_t)(m0 + arow + AROWS * i) * K + k0 + acol4 * 4);
        } else {
#pragma unroll
            for (int i = 0; i < BIT; ++i) {
                const size_t off = (size_t)(m0 + brow + BROWS * i) * K + k0 + bchunk * 8;
                aH[i] = *(const uint4v*)(Ah + off);
                aL[i] = *(const uint4v*)(Al + off);
            }
        }
#pragma unroll
        for (int i = 0; i < BIT; ++i) {
            const size_t off = (size_t)(n0 + brow + BROWS * i) * K + k0 + bchunk * 8;
            bH[i] = *(const uint4v*)(BhT + off);
            bL[i] = *(const uint4v*)(BlT + off);
        }
    };

    auto stage_to_lds = [&]() {
        if constexpr (A_F32) {
#pragma unroll
            for (int i = 0; i < AIT; ++i) {
                const int r = arow + AROWS * i;
                ushort4v h, l;
#pragma unroll
                for (int j = 0; j < 4; ++j) {
                    unsigned short hh, ll;
                    split_f32(aF[i][j], hh, ll);
                    h[j] = hh; l[j] = ll;
                }
                const int ck  = acol4 >> 1;
                const int sub = (acol4 & 1) * 4;
                const int off = r * BKT + ((ck ^ (r & XM)) << 3) + sub;
                *(ushort4v*)(sAh + off) = h;
                *(ushort4v*)(sAl + off) = l;
            }
        } else {
#pragma unroll
            for (int i = 0; i < BIT; ++i) {
                const int r   = brow + BROWS * i;
                const int off = r * BKT + ((bchunk ^ (r & XM)) << 3);
                *(uint4v*)(sAh + off) = aH[i];
                *(uint4v*)(sAl + off) = aL[i];
            }
        }
#pragma unroll
        for (int i = 0; i < BIT; ++i) {
            const int r   = brow + BROWS * i;
            const int off = r * BKT + ((bchunk ^ (r & XM)) << 3);
            *(uint4v*)(sBh + off) = bH[i];
            *(uint4v*)(sBl + off) = bL[i];
        }
    };

    load_tile(0);

    for (int kt = 0; kt < ktiles; ++kt) {
        __syncthreads();                 // prev compute done
        stage_to_lds();
        __syncthreads();                 // LDS ready
        if (kt + 1 < ktiles) load_tile(kt + 1);  // in flight across compute
#pragma unroll
        for (int kk = 0; kk < BKT / 32; ++kk) {
            const int ck = kk * 4 + kgrp;
            short8 fah[4], fal[4];
#pragma unroll
            for (int m = 0; m < 4; ++m) {
                const int r   = wm + m * 16 + (lane & 15);
                const int off = r * BKT + ((ck ^ (r & XM)) << 3);
                fah[m] = *(const short8*)(sAh + off);
                fal[m] = *(const short8*)(sAl + off);
            }
#pragma unroll
            for (int n = 0; n < 4; ++n) {
                const int r   = wn + n * 16 + (lane & 15);
                const int off = r * BKT + ((ck ^ (r & XM)) << 3);
                const short8 fbh = *(const short8*)(sBh + off);
                const short8 fbl = *(const short8*)(sBl + off);
#pragma unroll
                for (int m = 0; m < 4; ++m) {
                    acc[m][n] = __builtin_amdgcn_mfma_f32_16x16x32_bf16(fah[m], fbh, acc[m][n], 0, 0, 0);
                    acc[m][n] = __builtin_amdgcn_mfma_f32_16x16x32_bf16(fah[m], fbl, acc[m][n], 0, 0, 0);
                    acc[m][n] = __builtin_amdgcn_mfma_f32_16x16x32_bf16(fal[m], fbh, acc[m][n], 0, 0, 0);
                }
            }
        }
    }

    // Epilogue. C/D layout (verified): col = lane&15, row = (lane>>4)*4 + reg.
    const int col  = lane & 15;
    const int row4 = (lane >> 4) * 4;
#pragma unroll
    for (int n = 0; n < 4; ++n) {
        const int gn = n0 + wn + n * 16 + col;
        if constexpr (EPI == 0) {
            const float bv = bias[gn];
#pragma unroll
            for (int m = 0; m < 4; ++m) {
                const int gmb = m0 + wm + m * 16 + row4;
#pragma unroll
                for (int j = 0; j < 4; ++j) {
                    float v = acc[m][n][j] + bv;
                    v = fmaxf(v, 0.0f);
                    unsigned short hh, ll;
                    split_f32(v, hh, ll);
                    const size_t o = (size_t)(gmb + j) * ldC + gn;
                    Ch[o] = hh;
                    Cl[o] = ll;
                }
            }
        } else {
            float* Cp = Cf + (size_t)blockIdx.z * (size_t)gridDim.x * BM * ldC;
#pragma unroll
            for (int m = 0; m < 4; ++m) {
                const int gmb = m0 + wm + m * 16 + row4;
#pragma unroll
                for (int j = 0; j < 4; ++j) {
                    Cp[(size_t)(gmb + j) * ldC + gn] = acc[m][n][j];
                }
            }
        }
    }
}

// ---------------------------------------------------------------------------
// reduce: sum nplanes fp32 partials + bias -> relu -> split planes.
// One thread = 4 consecutive elements. ldmask = ldC-1 (power of 2).
// ---------------------------------------------------------------------------
__global__ __launch_bounds__(256) void reduce_relu_split(
        const float* __restrict__ P, size_t planeStride, int nplanes,
        const float* __restrict__ bias, int ldmask,
        unsigned short* __restrict__ Ch, unsigned short* __restrict__ Cl) {
    const size_t base = ((size_t)blockIdx.x * 256 + threadIdx.x) * 4;
    f32x4 s = *(const f32x4*)(P + base);
    for (int z = 1; z < nplanes; ++z)
        s += *(const f32x4*)(P + (size_t)z * planeStride + base);
    const int colb = (int)(base & (size_t)ldmask);
    const f32x4 b = *(const f32x4*)(bias + colb);
    ushort4v h, l;
#pragma unroll
    for (int j = 0; j < 4; ++j) {
        float v = fmaxf(s[j] + b[j], 0.0f);
        unsigned short hh, ll;
        split_f32(v, hh, ll);
        h[j] = hh; l[j] = ll;
    }
    *(ushort4v*)(Ch + base) = h;
    *(ushort4v*)(Cl + base) = l;
}

// ---------------------------------------------------------------------------
// GEMM3 finish: sum 4 partials [4][4096][384] + bias, crop N 384->324.
// grid = (3, 4096), block = 128.
// ---------------------------------------------------------------------------
__global__ __launch_bounds__(128) void reduce_bias_out(
        const float* __restrict__ P, const float* __restrict__ bias,
        float* __restrict__ out) {
    const int col = blockIdx.x * 128 + threadIdx.x;   // 0..383
    const int row = blockIdx.y;
    if (col >= 324) return;
    float s = bias[col];
#pragma unroll
    for (int z = 0; z < 4; ++z)
        s += P[((size_t)z * 4096 + row) * 384 + col];
    out[(size_t)row * 324 + col] = s;
}

// ---------------------------------------------------------------------------
// Workspace layout (bytes). Small path = 90,701,824 (known to fit, R2).
// Big path = 124,256,256 (P has 4 planes) — used only if ws_size allows.
// Overlays: C1 planes alias W1h region (dead after GEMM1);
//           C2 planes alias W1l region; GEMM2/3 partials reuse P region.
// ---------------------------------------------------------------------------
static constexpr size_t SZ_W1P  = (size_t)1024 * 12544 * 2;   // 25,690,112
static constexpr size_t SZ_W2P  = (size_t)1024 * 1024  * 2;   //  2,097,152
static constexpr size_t SZ_W3P  = (size_t)384  * 1024  * 2;   //    786,432
static constexpr size_t SZ_PLANE= (size_t)4096 * 1024 * 4;    // 16,777,216
static constexpr size_t SZ_CP   = (size_t)4096 * 1024 * 2;    //  8,388,608
static constexpr size_t OFF_W1H = 0;
static constexpr size_t OFF_W1L = OFF_W1H + SZ_W1P;
static constexpr size_t OFF_W2H = OFF_W1L + SZ_W1P;
static constexpr size_t OFF_W2L = OFF_W2H + SZ_W2P;
static constexpr size_t OFF_W3H = OFF_W2L + SZ_W2P;
static constexpr size_t OFF_W3L = OFF_W3H + SZ_W3P;
static constexpr size_t OFF_P   = OFF_W3L + SZ_W3P;
static constexpr size_t WS_SMALL = OFF_P + 2 * SZ_PLANE;      // 90,701,824
static constexpr size_t WS_BIG   = OFF_P + 4 * SZ_PLANE;      // 124,256,256
static constexpr size_t OFF_C1H = OFF_W1H;                    // alias W1h
static constexpr size_t OFF_C1L = OFF_W1H + SZ_CP;
static constexpr size_t OFF_C2H = OFF_W1L;                    // alias W1l
static constexpr size_t OFF_C2L = OFF_W1L + SZ_CP;

extern "C" void kernel_launch(void* const* d_in, const int* in_sizes, int n_in,
                              void* d_out, int out_size, void* d_ws, size_t ws_size,
                              hipStream_t stream) {
    const float* features = (const float*)d_in[0];
    // d_in[1] = batch_indices: mathematically dead (permutation cancels).
    const float* w1 = (const float*)d_in[2];
    const float* b1 = (const float*)d_in[3];
    const float* w2 = (const float*)d_in[4];
    const float* b2 = (const float*)d_in[5];
    const float* w3 = (const float*)d_in[6];
    const float* b3 = (const float*)d_in[7];
    float* out = (float*)d_out;

    if (ws_size < WS_SMALL) return;  // visible failure rather than corruption
    const bool big = (ws_size >= WS_BIG);   // deterministic per deployment

    char* ws = (char*)d_ws;
    unsigned short* W1h = (unsigned short*)(ws + OFF_W1H);
    unsigned short* W1l = (unsigned short*)(ws + OFF_W1L);
    unsigned short* W2h = (unsigned short*)(ws + OFF_W2H);
    unsigned short* W2l = (unsigned short*)(ws + OFF_W2L);
    unsigned short* W3h = (unsigned short*)(ws + OFF_W3H);
    unsigned short* W3l = (unsigned short*)(ws + OFF_W3L);
    unsigned short* C1h = (unsigned short*)(ws + OFF_C1H);
    unsigned short* C1l = (unsigned short*)(ws + OFF_C1L);
    unsigned short* C2h = (unsigned short*)(ws + OFF_C2H);
    unsigned short* C2l = (unsigned short*)(ws + OFF_C2L);
    float*          P   = (float*)(ws + OFF_P);

    // Weight converts (every launch — same work per call, graph-safe).
    convert_w_t<<<dim3(1024 / 64, 12544 / 64), 256, 0, stream>>>(w1, W1h, W1l, 12544, 1024);
    convert_w_t<<<dim3(1024 / 64, 1024  / 64), 256, 0, stream>>>(w2, W2h, W2l, 1024, 1024);
    convert_w_t<<<dim3(384  / 64, 1024  / 64), 256, 0, stream>>>(w3, W3h, W3l, 1024, 324);

    // L1: [4096,12544]@[12544,1024] -> fp32 partials.
    if (big) {
        // BK=32, split-K=4: 1024 blocks, 32KB LDS -> 4 resident blocks/CU.
        gemm3split<true, 1, 32><<<dim3(4096 / BM, 1024 / BN, 4), 256, 0, stream>>>(
            features, nullptr, nullptr, W1h, W1l, nullptr, nullptr, nullptr, P,
            12544, 98, 1024);
        reduce_relu_split<<<4096, 256, 0, stream>>>(
            P, (size_t)4096 * 1024, 4, b1, 1023, C1h, C1l);
    } else {
        // Exact R2 config (known-good fallback).
        gemm3split<true, 1, 64><<<dim3(4096 / BM, 1024 / BN, 2), 256, 0, stream>>>(
            features, nullptr, nullptr, W1h, W1l, nullptr, nullptr, nullptr, P,
            12544, 98, 1024);
        reduce_relu_split<<<4096, 256, 0, stream>>>(
            P, (size_t)4096 * 1024, 2, b1, 1023, C1h, C1l);
    }

    // L2: [4096,1024]@[1024,1024], split-K=2 -> partials -> reduce+relu.
    gemm3split<false, 1, 64><<<dim3(4096 / BM, 1024 / BN, 2), 256, 0, stream>>>(
        nullptr, C1h, C1l, W2h, W2l, nullptr, nullptr, nullptr, P,
        1024, 8, 1024);
    reduce_relu_split<<<4096, 256, 0, stream>>>(
        P, (size_t)4096 * 1024, 2, b2, 1023, C2h, C2l);

    // L3: [4096,1024]@[1024,384pad], split-K=4 -> fp32 partials P[4][4096][384]
    gemm3split<false, 1, 64><<<dim3(4096 / BM, 384 / BN, 4), 256, 0, stream>>>(
        nullptr, C2h, C2l, W3h, W3l, nullptr, nullptr, nullptr, P,
        1024, 4, 384);
    // reduce + b3, crop 384 -> 324
    reduce_bias_out<<<dim3(3, 4096), 128, 0, stream>>>(P, b3, out);
}

// Round 6
// 655.285 us; speedup vs baseline: 2.3993x; 2.3993x over previous
//
#include <hip/hip_runtime.h>

// ROIBBoxHead: out = relu(relu(X@W1+b1)@W2+b2)@W3+b3
// X=[4096,12544] fp32, W1=[12544,1024], W2=[1024,1024], W3=[1024,324].
// Split-bf16 emulated-fp32 GEMM on the MFMA pipe:
//   a*b ~= ah*bh + ah*bl + al*bh   (error ~2^-16 relative)
// 128x128 tile, BK=64, 4 waves, XOR-swizzled LDS (r&7, conflict-free).
// R4/R5/R6: exact R2 structure, but inner op = mfma_f32_32x32x16_bf16
// (48 MFMA @8cyc vs 96 @4.85cyc per K-tile -> -17% matrix-pipe cycles).
// R3's BK=32/launch_bounds(,4) path DELETED (VGPR=64 spill catastrophe,
// 2.6e7 bank conflicts).

typedef __attribute__((ext_vector_type(4)))  float          f32x4;
typedef __attribute__((ext_vector_type(16))) float          f32x16;
typedef __attribute__((ext_vector_type(8)))  short          short8;
typedef __attribute__((ext_vector_type(4)))  unsigned int   uint4v;
typedef __attribute__((ext_vector_type(4)))  unsigned short ushort4v;
typedef __attribute__((ext_vector_type(8)))  unsigned short ushort8v;

#define BM 128
#define BN 128
#define BK 64

// Truncation split: x ~= hi + lo, |x - hi - lo| <= 2^-16 |x|.
__device__ __forceinline__ void split_f32(float x, unsigned short& h, unsigned short& l) {
    unsigned int u = __float_as_uint(x);
    h = (unsigned short)(u >> 16);
    float hf = __uint_as_float(u & 0xFFFF0000u);
    l = (unsigned short)(__float_as_uint(x - hf) >> 16);
}

// ---------------------------------------------------------------------------
// Weight conversion: W[K][N] fp32 -> WhT[Npad][K], WlT[Npad][K] bf16 planes.
// 64x64 LDS transpose tile; vectorized ushort8 stores along K.
// grid = (Npad/64, K/64), block = 256.
// ---------------------------------------------------------------------------
__global__ __launch_bounds__(256) void convert_w_t(const float* __restrict__ W,
                                                   unsigned short* __restrict__ WhT,
                                                   unsigned short* __restrict__ WlT,
                                                   int K, int N) {
    __shared__ float tile[64][65];
    const int k0 = blockIdx.y * 64;
    const int n0 = blockIdx.x * 64;
    const int tid = threadIdx.x;
    const int kr = tid >> 4;          // 0..15
    const int nc = (tid & 15) * 4;    // 0..60
#pragma unroll
    for (int i = 0; i < 4; ++i) {
        const int k = kr + 16 * i;
        f32x4 v = (f32x4){0.f, 0.f, 0.f, 0.f};
        if (n0 + nc < N) v = *(const f32x4*)(W + (size_t)(k0 + k) * N + n0 + nc);
        tile[k][nc + 0] = v[0];
        tile[k][nc + 1] = v[1];
        tile[k][nc + 2] = v[2];
        tile[k][nc + 3] = v[3];
    }
    __syncthreads();
    const int nr = tid >> 2;          // 0..63
    const int kc = (tid & 3) * 16;    // 0..48
    ushort8v h0, h1, l0, l1;
#pragma unroll
    for (int j = 0; j < 8; ++j) {
        unsigned short hh, ll;
        split_f32(tile[kc + j][nr], hh, ll);
        h0[j] = hh; l0[j] = ll;
        split_f32(tile[kc + 8 + j][nr], hh, ll);
        h1[j] = hh; l1[j] = ll;
    }
    const size_t o = (size_t)(n0 + nr) * K + k0 + kc;
    *(ushort8v*)(WhT + o)     = h0;
    *(ushort8v*)(WhT + o + 8) = h1;
    *(ushort8v*)(WlT + o)     = l0;
    *(ushort8v*)(WlT + o + 8) = l1;
}

// ---------------------------------------------------------------------------
// Split-bf16 GEMM: C = A @ B (K-slice per blockIdx.z), BK=64.
//   A_F32: A fp32, converted hi/lo during staging; else A given as planes.
//   EPI=0: +bias, relu, write bf16 hi/lo planes (stride ldC)
//   EPI=1: raw fp32 partial to Cf + z*gridDim.x*BM*ldC (N padded, no guard)
// Inner op: v_mfma_f32_32x32x16_bf16. Per wave: 2x2 frags of 32x32.
// A-frag: row = lane&31, k-chunk = lane>>5 (8 bf16). B-frag symmetric.
// C/D (verified m74/m101): col=lane&31, row=(reg&3)+8*(reg>>2)+4*(lane>>5).
// ---------------------------------------------------------------------------
template<bool A_F32, int EPI>
__global__ __launch_bounds__(256, 2)
void gemm3split(const float* __restrict__ A32,
                const unsigned short* __restrict__ Ah,
                const unsigned short* __restrict__ Al,
                const unsigned short* __restrict__ BhT,
                const unsigned short* __restrict__ BlT,
                const float* __restrict__ bias,
                unsigned short* __restrict__ Ch,
                unsigned short* __restrict__ Cl,
                float* __restrict__ Cf,
                int K, int ktiles, int ldC) {
    const int tid   = threadIdx.x;
    const int lane  = tid & 63;
    const int wave  = tid >> 6;
    const int lrow  = lane & 31;
    const int khalf = lane >> 5;
    const int m0 = blockIdx.x * BM;
    const int n0 = blockIdx.y * BN;
    const int kt_base = blockIdx.z * ktiles;
    const int wm = (wave >> 1) * 64;
    const int wn = (wave & 1) * 64;

    __shared__ __align__(16) unsigned short sAh[BM * BK];
    __shared__ __align__(16) unsigned short sAl[BM * BK];
    __shared__ __align__(16) unsigned short sBh[BN * BK];
    __shared__ __align__(16) unsigned short sBl[BN * BK];

    f32x16 acc[2][2];
#pragma unroll
    for (int m = 0; m < 2; ++m)
#pragma unroll
        for (int n = 0; n < 2; ++n)
#pragma unroll
            for (int i = 0; i < 16; ++i) acc[m][n][i] = 0.0f;

    const int arow   = tid >> 4;   // A_F32 staging: 16 rows x 16 chunks(4 floats)
    const int acol4  = tid & 15;
    const int brow   = tid >> 3;   // bf16 staging: 32 rows x 8 chunks(8 bf16)
    const int bchunk = tid & 7;

    f32x4  aF[8];
    uint4v aH[4], aL[4];
    uint4v bH[4], bL[4];

    auto load_tile = [&](int kt) {
        const int k0 = (kt_base + kt) * BK;
        if constexpr (A_F32) {
#pragma unroll
            for (int i = 0; i < 8; ++i)
                aF[i] = *(const f32x4*)(A32 + (size_t)(m0 + arow + 16 * i) * K + k0 + acol4 * 4);
        } else {
#pragma unroll
            for (int i = 0; i < 4; ++i) {
                const size_t off = (size_t)(m0 + brow + 32 * i) * K + k0 + bchunk * 8;
                aH[i] = *(const uint4v*)(Ah + off);
                aL[i] = *(const uint4v*)(Al + off);
            }
        }
#pragma unroll
        for (int i = 0; i < 4; ++i) {
            const size_t off = (size_t)(n0 + brow + 32 * i) * K + k0 + bchunk * 8;
            bH[i] = *(const uint4v*)(BhT + off);
            bL[i] = *(const uint4v*)(BlT + off);
        }
    };

    auto stage_to_lds = [&]() {
        if constexpr (A_F32) {
#pragma unroll
            for (int i = 0; i < 8; ++i) {
                const int r = arow + 16 * i;
                ushort4v h, l;
#pragma unroll
                for (int j = 0; j < 4; ++j) {
                    unsigned short hh, ll;
                    split_f32(aF[i][j], hh, ll);
                    h[j] = hh; l[j] = ll;
                }
                const int ck  = acol4 >> 1;
                const int sub = (acol4 & 1) * 4;
                const int off = r * BK + ((ck ^ (r & 7)) << 3) + sub;
                *(ushort4v*)(sAh + off) = h;
                *(ushort4v*)(sAl + off) = l;
            }
        } else {
#pragma unroll
            for (int i = 0; i < 4; ++i) {
                const int r   = brow + 32 * i;
                const int off = r * BK + ((bchunk ^ (r & 7)) << 3);
                *(uint4v*)(sAh + off) = aH[i];
                *(uint4v*)(sAl + off) = aL[i];
            }
        }
#pragma unroll
        for (int i = 0; i < 4; ++i) {
            const int r   = brow + 32 * i;
            const int off = r * BK + ((bchunk ^ (r & 7)) << 3);
            *(uint4v*)(sBh + off) = bH[i];
            *(uint4v*)(sBl + off) = bL[i];
        }
    };

    load_tile(0);

    for (int kt = 0; kt < ktiles; ++kt) {
        __syncthreads();                 // prev compute done
        stage_to_lds();
        __syncthreads();                 // LDS ready
        if (kt + 1 < ktiles) load_tile(kt + 1);  // in flight across compute
#pragma unroll
        for (int kk = 0; kk < 4; ++kk) {         // 4 K-steps of 16
            const int ck = kk * 2 + khalf;       // 8-bf16 chunk index in row
            short8 fah[2], fal[2], fbh[2], fbl[2];
#pragma unroll
            for (int mf = 0; mf < 2; ++mf) {
                const int r   = wm + mf * 32 + lrow;
                const int off = r * BK + ((ck ^ (r & 7)) << 3);
                fah[mf] = *(const short8*)(sAh + off);
                fal[mf] = *(const short8*)(sAl + off);
            }
#pragma unroll
            for (int nf = 0; nf < 2; ++nf) {
                const int r   = wn + nf * 32 + lrow;
                const int off = r * BK + ((ck ^ (r & 7)) << 3);
                fbh[nf] = *(const short8*)(sBh + off);
                fbl[nf] = *(const short8*)(sBl + off);
            }
#pragma unroll
            for (int nf = 0; nf < 2; ++nf)
#pragma unroll
                for (int mf = 0; mf < 2; ++mf) {
                    acc[mf][nf] = __builtin_amdgcn_mfma_f32_32x32x16_bf16(fah[mf], fbh[nf], acc[mf][nf], 0, 0, 0);
                    acc[mf][nf] = __builtin_amdgcn_mfma_f32_32x32x16_bf16(fah[mf], fbl[nf], acc[mf][nf], 0, 0, 0);
                    acc[mf][nf] = __builtin_amdgcn_mfma_f32_32x32x16_bf16(fal[mf], fbh[nf], acc[mf][nf], 0, 0, 0);
                }
        }
    }

    // Epilogue. 32x32 C/D: col = lane&31, row = (reg&3)+8*(reg>>2)+4*khalf.
#pragma unroll
    for (int nf = 0; nf < 2; ++nf) {
        const int gn = n0 + wn + nf * 32 + lrow;
        if constexpr (EPI == 0) {
            const float bv = bias[gn];
#pragma unroll
            for (int mf = 0; mf < 2; ++mf) {
                const int gmb = m0 + wm + mf * 32 + 4 * khalf;
#pragma unroll
                for (int reg = 0; reg < 16; ++reg) {
                    const int grow = gmb + (reg & 3) + 8 * (reg >> 2);
                    float v = acc[mf][nf][reg] + bv;
                    v = fmaxf(v, 0.0f);
                    unsigned short hh, ll;
                    split_f32(v, hh, ll);
                    const size_t o = (size_t)grow * ldC + gn;
                    Ch[o] = hh;
                    Cl[o] = ll;
                }
            }
        } else {
            float* Cp = Cf + (size_t)blockIdx.z * (size_t)gridDim.x * BM * ldC;
#pragma unroll
            for (int mf = 0; mf < 2; ++mf) {
                const int gmb = m0 + wm + mf * 32 + 4 * khalf;
#pragma unroll
                for (int reg = 0; reg < 16; ++reg) {
                    const int grow = gmb + (reg & 3) + 8 * (reg >> 2);
                    Cp[(size_t)grow * ldC + gn] = acc[mf][nf][reg];
                }
            }
        }
    }
}

// ---------------------------------------------------------------------------
// reduce: sum nplanes fp32 partials + bias -> relu -> split planes.
// One thread = 4 consecutive elements. ldmask = ldC-1 (power of 2).
// ---------------------------------------------------------------------------
__global__ __launch_bounds__(256) void reduce_relu_split(
        const float* __restrict__ P, size_t planeStride, int nplanes,
        const float* __restrict__ bias, int ldmask,
        unsigned short* __restrict__ Ch, unsigned short* __restrict__ Cl) {
    const size_t base = ((size_t)blockIdx.x * 256 + threadIdx.x) * 4;
    f32x4 s = *(const f32x4*)(P + base);
    for (int z = 1; z < nplanes; ++z)
        s += *(const f32x4*)(P + (size_t)z * planeStride + base);
    const int colb = (int)(base & (size_t)ldmask);
    const f32x4 b = *(const f32x4*)(bias + colb);
    ushort4v h, l;
#pragma unroll
    for (int j = 0; j < 4; ++j) {
        float v = fmaxf(s[j] + b[j], 0.0f);
        unsigned short hh, ll;
        split_f32(v, hh, ll);
        h[j] = hh; l[j] = ll;
    }
    *(ushort4v*)(Ch + base) = h;
    *(ushort4v*)(Cl + base) = l;
}

// ---------------------------------------------------------------------------
// GEMM3 finish: sum 4 partials [4][4096][384] + bias, crop N 384->324.
// grid = (3, 4096), block = 128.
// ---------------------------------------------------------------------------
__global__ __launch_bounds__(128) void reduce_bias_out(
        const float* __restrict__ P, const float* __restrict__ bias,
        float* __restrict__ out) {
    const int col = blockIdx.x * 128 + threadIdx.x;   // 0..383
    const int row = blockIdx.y;
    if (col >= 324) return;
    float s = bias[col];
#pragma unroll
    for (int z = 0; z < 4; ++z)
        s += P[((size_t)z * 4096 + row) * 384 + col];
    out[(size_t)row * 324 + col] = s;
}

// ---------------------------------------------------------------------------
// Workspace layout (bytes). Total = 90,701,824 (R2 layout, known to fit).
// Overlays: C1 planes alias W1h region (dead after GEMM1);
//           C2 planes alias W1l region; GEMM3 partials reuse P region.
// ---------------------------------------------------------------------------
static constexpr size_t SZ_W1P  = (size_t)1024 * 12544 * 2;   // 25,690,112
static constexpr size_t SZ_W2P  = (size_t)1024 * 1024  * 2;   //  2,097,152
static constexpr size_t SZ_W3P  = (size_t)384  * 1024  * 2;   //    786,432
static constexpr size_t SZ_P    = (size_t)2 * 4096 * 1024 * 4;// 33,554,432
static constexpr size_t SZ_CP   = (size_t)4096 * 1024 * 2;    //  8,388,608
static constexpr size_t OFF_W1H = 0;
static constexpr size_t OFF_W1L = OFF_W1H + SZ_W1P;
static constexpr size_t OFF_W2H = OFF_W1L + SZ_W1P;
static constexpr size_t OFF_W2L = OFF_W2H + SZ_W2P;
static constexpr size_t OFF_W3H = OFF_W2L + SZ_W2P;
static constexpr size_t OFF_W3L = OFF_W3H + SZ_W3P;
static constexpr size_t OFF_P   = OFF_W3L + SZ_W3P;
static constexpr size_t WS_NEED = OFF_P + SZ_P;               // 90,701,824
static constexpr size_t OFF_C1H = OFF_W1H;                    // alias W1h
static constexpr size_t OFF_C1L = OFF_W1H + SZ_CP;
static constexpr size_t OFF_C2H = OFF_W1L;                    // alias W1l
static constexpr size_t OFF_C2L = OFF_W1L + SZ_CP;

extern "C" void kernel_launch(void* const* d_in, const int* in_sizes, int n_in,
                              void* d_out, int out_size, void* d_ws, size_t ws_size,
                              hipStream_t stream) {
    const float* features = (const float*)d_in[0];
    // d_in[1] = batch_indices: mathematically dead (permutation cancels).
    const float* w1 = (const float*)d_in[2];
    const float* b1 = (const float*)d_in[3];
    const float* w2 = (const float*)d_in[4];
    const float* b2 = (const float*)d_in[5];
    const float* w3 = (const float*)d_in[6];
    const float* b3 = (const float*)d_in[7];
    float* out = (float*)d_out;

    if (ws_size < WS_NEED) return;   // visible failure rather than corruption

    char* ws = (char*)d_ws;
    unsigned short* W1h = (unsigned short*)(ws + OFF_W1H);
    unsigned short* W1l = (unsigned short*)(ws + OFF_W1L);
    unsigned short* W2h = (unsigned short*)(ws + OFF_W2H);
    unsigned short* W2l = (unsigned short*)(ws + OFF_W2L);
    unsigned short* W3h = (unsigned short*)(ws + OFF_W3H);
    unsigned short* W3l = (unsigned short*)(ws + OFF_W3L);
    unsigned short* C1h = (unsigned short*)(ws + OFF_C1H);
    unsigned short* C1l = (unsigned short*)(ws + OFF_C1L);
    unsigned short* C2h = (unsigned short*)(ws + OFF_C2H);
    unsigned short* C2l = (unsigned short*)(ws + OFF_C2L);
    float*          P   = (float*)(ws + OFF_P);

    // Weight converts (every launch — same work per call, graph-safe).
    convert_w_t<<<dim3(1024 / 64, 12544 / 64), 256, 0, stream>>>(w1, W1h, W1l, 12544, 1024);
    convert_w_t<<<dim3(1024 / 64, 1024  / 64), 256, 0, stream>>>(w2, W2h, W2l, 1024, 1024);
    convert_w_t<<<dim3(384  / 64, 1024  / 64), 256, 0, stream>>>(w3, W3h, W3l, 1024, 324);

    // L1: [4096,12544]@[12544,1024], split-K=2 -> fp32 partials P[2][4096][1024]
    gemm3split<true, 1><<<dim3(4096 / BM, 1024 / BN, 2), 256, 0, stream>>>(
        features, nullptr, nullptr, W1h, W1l, nullptr, nullptr, nullptr, P,
        12544, 98, 1024);
    // reduce + b1 + relu -> C1 planes
    reduce_relu_split<<<4096, 256, 0, stream>>>(
        P, (size_t)4096 * 1024, 2, b1, 1023, C1h, C1l);

    // L2: [4096,1024]@[1024,1024] -> relu -> C2 planes (no split-K, R2 config)
    gemm3split<false, 0><<<dim3(4096 / BM, 1024 / BN, 1), 256, 0, stream>>>(
        nullptr, C1h, C1l, W2h, W2l, b2, C2h, C2l, nullptr,
        1024, 16, 1024);

    // L3: [4096,1024]@[1024,384pad], split-K=4 -> fp32 partials P[4][4096][384]
    gemm3split<false, 1><<<dim3(4096 / BM, 384 / BN, 4), 256, 0, stream>>>(
        nullptr, C2h, C2l, W3h, W3l, nullptr, nullptr, nullptr, P,
        1024, 4, 384);
    // reduce + b3, crop 384 -> 324
    reduce_bias_out<<<dim3(3, 4096), 128, 0, stream>>>(P, b3, out);
}

// Round 11
// 625.696 us; speedup vs baseline: 2.5128x; 1.0473x over previous
//
#include <hip/hip_runtime.h>

// ROIBBoxHead: out = relu(relu(X@W1+b1)@W2+b2)@W3+b3
// X=[4096,12544] fp32, W1=[12544,1024], W2=[1024,1024], W3=[1024,324].
// Split-bf16 emulated-fp32 GEMM on the MFMA pipe:
//   a*b ~= ah*bh + ah*bl + al*bh   (error ~2^-16 relative)
// 128x128 tile, BK=64, 4 waves, mfma_f32_16x16x32_bf16 (R2-proven: 0 bank
// conflicts; 32x32 variant REVERTED — R6 measured 2.57e7 conflicts, +15us).
// R7..R11: fused dataflow. Every GEMM writes fp32 split-K partials; the
// NEXT GEMM's A-staging reads 2 partial planes + bias, applies relu + hi/lo
// split on the fly (deletes reduce kernels + bf16 C plane round-trips).
// ws_size >= 124,256,256 proven by R3's run.

typedef __attribute__((ext_vector_type(4)))  float          f32x4;
typedef __attribute__((ext_vector_type(8)))  short          short8;
typedef __attribute__((ext_vector_type(4)))  unsigned int   uint4v;
typedef __attribute__((ext_vector_type(4)))  unsigned short ushort4v;
typedef __attribute__((ext_vector_type(8)))  unsigned short ushort8v;

#define BM 128
#define BN 128
#define BK 64

// Truncation split: x ~= hi + lo, |x - hi - lo| <= 2^-16 |x|.
__device__ __forceinline__ void split_f32(float x, unsigned short& h, unsigned short& l) {
    unsigned int u = __float_as_uint(x);
    h = (unsigned short)(u >> 16);
    float hf = __uint_as_float(u & 0xFFFF0000u);
    l = (unsigned short)(__float_as_uint(x - hf) >> 16);
}

// ---------------------------------------------------------------------------
// Weight conversion: W[K][N] fp32 -> WhT[Npad][K], WlT[Npad][K] bf16 planes.
// 64x64 LDS transpose tile; vectorized ushort8 stores along K.
// grid = (Npad/64, K/64), block = 256.
// ---------------------------------------------------------------------------
__global__ __launch_bounds__(256) void convert_w_t(const float* __restrict__ W,
                                                   unsigned short* __restrict__ WhT,
                                                   unsigned short* __restrict__ WlT,
                                                   int K, int N) {
    __shared__ float tile[64][65];
    const int k0 = blockIdx.y * 64;
    const int n0 = blockIdx.x * 64;
    const int tid = threadIdx.x;
    const int kr = tid >> 4;          // 0..15
    const int nc = (tid & 15) * 4;    // 0..60
#pragma unroll
    for (int i = 0; i < 4; ++i) {
        const int k = kr + 16 * i;
        f32x4 v = (f32x4){0.f, 0.f, 0.f, 0.f};
        if (n0 + nc < N) v = *(const f32x4*)(W + (size_t)(k0 + k) * N + n0 + nc);
        tile[k][nc + 0] = v[0];
        tile[k][nc + 1] = v[1];
        tile[k][nc + 2] = v[2];
        tile[k][nc + 3] = v[3];
    }
    __syncthreads();
    const int nr = tid >> 2;          // 0..63
    const int kc = (tid & 3) * 16;    // 0..48
    ushort8v h0, h1, l0, l1;
#pragma unroll
    for (int j = 0; j < 8; ++j) {
        unsigned short hh, ll;
        split_f32(tile[kc + j][nr], hh, ll);
        h0[j] = hh; l0[j] = ll;
        split_f32(tile[kc + 8 + j][nr], hh, ll);
        h1[j] = hh; l1[j] = ll;
    }
    const size_t o = (size_t)(n0 + nr) * K + k0 + kc;
    *(ushort8v*)(WhT + o)     = h0;
    *(ushort8v*)(WhT + o + 8) = h1;
    *(ushort8v*)(WlT + o)     = l0;
    *(ushort8v*)(WlT + o + 8) = l1;
}

// ---------------------------------------------------------------------------
// Split-bf16 GEMM: Cpartial[z] = A @ B (K-slice per blockIdx.z), BK=64.
//   ASRC=0: A = fp32 matrix (X), split hi/lo during staging.
//   ASRC=1: A = relu(P0[off] + P1[off] + abias[k]) computed during staging
//           (fuses the previous layer's split-K reduce + bias + relu).
// Output: raw fp32 partial to Cf + z*gridDim.x*BM*ldC (N padded, no guard).
// Inner op: mfma_f32_16x16x32_bf16 (R2-proven layout, 0 bank conflicts).
// ---------------------------------------------------------------------------
template<int ASRC>
__global__ __launch_bounds__(256, 2)
void gemm3split(const float* __restrict__ A0,
                const float* __restrict__ A1,
                const float* __restrict__ abias,
                const unsigned short* __restrict__ BhT,
                const unsigned short* __restrict__ BlT,
                float* __restrict__ Cf,
                int K, int ktiles, int ldC) {
    const int tid  = threadIdx.x;
    const int lane = tid & 63;
    const int wave = tid >> 6;
    const int kgrp = lane >> 4;
    const int m0 = blockIdx.x * BM;
    const int n0 = blockIdx.y * BN;
    const int kt_base = blockIdx.z * ktiles;
    const int wm = (wave >> 1) * 64;
    const int wn = (wave & 1) * 64;

    __shared__ __align__(16) unsigned short sAh[BM * BK];
    __shared__ __align__(16) unsigned short sAl[BM * BK];
    __shared__ __align__(16) unsigned short sBh[BN * BK];
    __shared__ __align__(16) unsigned short sBl[BN * BK];

    f32x4 acc[4][4];
#pragma unroll
    for (int m = 0; m < 4; ++m)
#pragma unroll
        for (int n = 0; n < 4; ++n) acc[m][n] = (f32x4){0.f, 0.f, 0.f, 0.f};

    const int arow   = tid >> 4;   // A staging: 16 rows x 16 chunks(4 floats)
    const int acol4  = tid & 15;
    const int brow   = tid >> 3;   // B staging: 32 rows x 8 chunks(8 bf16)
    const int bchunk = tid & 7;

    f32x4  aF[8];                  // plane-0 (or X)
    f32x4  aG[8];                  // plane-1 (ASRC=1 only)
    f32x4  aB;                     // bias chunk (ASRC=1 only)
    uint4v bH[4], bL[4];

    auto load_tile = [&](int kt) {
        const int k0 = (kt_base + kt) * BK;
#pragma unroll
        for (int i = 0; i < 8; ++i) {
            const size_t off = (size_t)(m0 + arow + 16 * i) * K + k0 + acol4 * 4;
            aF[i] = *(const f32x4*)(A0 + off);
            if constexpr (ASRC == 1) aG[i] = *(const f32x4*)(A1 + off);
        }
        if constexpr (ASRC == 1) aB = *(const f32x4*)(abias + k0 + acol4 * 4);
#pragma unroll
        for (int i = 0; i < 4; ++i) {
            const size_t off = (size_t)(n0 + brow + 32 * i) * K + k0 + bchunk * 8;
            bH[i] = *(const uint4v*)(BhT + off);
            bL[i] = *(const uint4v*)(BlT + off);
        }
    };

    auto stage_to_lds = [&]() {
#pragma unroll
        for (int i = 0; i < 8; ++i) {
            const int r = arow + 16 * i;
            ushort4v h, l;
#pragma unroll
            for (int j = 0; j < 4; ++j) {
                float v = aF[i][j];
                if constexpr (ASRC == 1) v = fmaxf(v + aG[i][j] + aB[j], 0.0f);
                unsigned short hh, ll;
                split_f32(v, hh, ll);
                h[j] = hh; l[j] = ll;
            }
            const int ck  = acol4 >> 1;
            const int sub = (acol4 & 1) * 4;
            const int off = r * BK + ((ck ^ (r & 7)) << 3) + sub;
            *(ushort4v*)(sAh + off) = h;
            *(ushort4v*)(sAl + off) = l;
        }
#pragma unroll
        for (int i = 0; i < 4; ++i) {
            const int r   = brow + 32 * i;
            const int off = r * BK + ((bchunk ^ (r & 7)) << 3);
            *(uint4v*)(sBh + off) = bH[i];
            *(uint4v*)(sBl + off) = bL[i];
        }
    };

    load_tile(0);

    for (int kt = 0; kt < ktiles; ++kt) {
        __syncthreads();                 // prev compute done
        stage_to_lds();
        __syncthreads();                 // LDS ready
        if (kt + 1 < ktiles) load_tile(kt + 1);  // in flight across compute
#pragma unroll
        for (int kk = 0; kk < BK / 32; ++kk) {
            const int ck = kk * 4 + kgrp;
            short8 fah[4], fal[4];
#pragma unroll
            for (int m = 0; m < 4; ++m) {
                const int r   = wm + m * 16 + (lane & 15);
                const int off = r * BK + ((ck ^ (r & 7)) << 3);
                fah[m] = *(const short8*)(sAh + off);
                fal[m] = *(const short8*)(sAl + off);
            }
#pragma unroll
            for (int n = 0; n < 4; ++n) {
                const int r   = wn + n * 16 + (lane & 15);
                const int off = r * BK + ((ck ^ (r & 7)) << 3);
                const short8 fbh = *(const short8*)(sBh + off);
                const short8 fbl = *(const short8*)(sBl + off);
#pragma unroll
                for (int m = 0; m < 4; ++m) {
                    acc[m][n] = __builtin_amdgcn_mfma_f32_16x16x32_bf16(fah[m], fbh, acc[m][n], 0, 0, 0);
                    acc[m][n] = __builtin_amdgcn_mfma_f32_16x16x32_bf16(fah[m], fbl, acc[m][n], 0, 0, 0);
                    acc[m][n] = __builtin_amdgcn_mfma_f32_16x16x32_bf16(fal[m], fbh, acc[m][n], 0, 0, 0);
                }
            }
        }
    }

    // Epilogue: raw fp32 partial. C/D layout (verified):
    // col = lane&15, row = (lane>>4)*4 + reg.
    const int col  = lane & 15;
    const int row4 = (lane >> 4) * 4;
    float* Cp = Cf + (size_t)blockIdx.z * (size_t)gridDim.x * BM * ldC;
#pragma unroll
    for (int n = 0; n < 4; ++n) {
        const int gn = n0 + wn + n * 16 + col;
#pragma unroll
        for (int m = 0; m < 4; ++m) {
            const int gmb = m0 + wm + m * 16 + row4;
#pragma unroll
            for (int j = 0; j < 4; ++j) {
                Cp[(size_t)(gmb + j) * ldC + gn] = acc[m][n][j];
            }
        }
    }
}

// ---------------------------------------------------------------------------
// Final: sum 4 partials [4][4096][384] + bias, crop N 384->324.
// grid = (3, 4096), block = 128.
// ---------------------------------------------------------------------------
__global__ __launch_bounds__(128) void reduce_bias_out(
        const float* __restrict__ P, const float* __restrict__ bias,
        float* __restrict__ out) {
    const int col = blockIdx.x * 128 + threadIdx.x;   // 0..383
    const int row = blockIdx.y;
    if (col >= 324) return;
    float s = bias[col];
#pragma unroll
    for (int z = 0; z < 4; ++z)
        s += P[((size_t)z * 4096 + row) * 384 + col];
    out[(size_t)row * 324 + col] = s;
}

// ---------------------------------------------------------------------------
// Workspace layout (bytes). Total = 124,256,256 (proven to fit by R3's run).
//   W planes:           [0 .. 57,147,392)
//   P1 (2 fp32 planes): [57,147,392 .. 90,701,824)   GEMM1 out / GEMM2 in
//   P2 (2 fp32 planes): [90,701,824 .. 124,256,256)  GEMM2 out / GEMM3 in
//   P3 (4x4096x384 f32 = 25,165,824) aliases P1 (dead by GEMM3: GEMM3
//   reads P2, writes P3; P1 no longer referenced).
// ---------------------------------------------------------------------------
static constexpr size_t SZ_W1P   = (size_t)1024 * 12544 * 2;   // 25,690,112
static constexpr size_t SZ_W2P   = (size_t)1024 * 1024  * 2;   //  2,097,152
static constexpr size_t SZ_W3P   = (size_t)384  * 1024  * 2;   //    786,432
static constexpr size_t SZ_PLANE = (size_t)4096 * 1024 * 4;    // 16,777,216
static constexpr size_t OFF_W1H  = 0;
static constexpr size_t OFF_W1L  = OFF_W1H + SZ_W1P;
static constexpr size_t OFF_W2H  = OFF_W1L + SZ_W1P;
static constexpr size_t OFF_W2L  = OFF_W2H + SZ_W2P;
static constexpr size_t OFF_W3H  = OFF_W2L + SZ_W2P;
static constexpr size_t OFF_W3L  = OFF_W3H + SZ_W3P;
static constexpr size_t OFF_P1   = OFF_W3L + SZ_W3P;           // 57,147,392
static constexpr size_t OFF_P2   = OFF_P1 + 2 * SZ_PLANE;      // 90,701,824
static constexpr size_t WS_NEED  = OFF_P2 + 2 * SZ_PLANE;      // 124,256,256
static constexpr size_t OFF_P3   = OFF_P1;                     // alias P1

extern "C" void kernel_launch(void* const* d_in, const int* in_sizes, int n_in,
                              void* d_out, int out_size, void* d_ws, size_t ws_size,
                              hipStream_t stream) {
    const float* features = (const float*)d_in[0];
    // d_in[1] = batch_indices: mathematically dead (permutation cancels).
    const float* w1 = (const float*)d_in[2];
    const float* b1 = (const float*)d_in[3];
    const float* w2 = (const float*)d_in[4];
    const float* b2 = (const float*)d_in[5];
    const float* w3 = (const float*)d_in[6];
    const float* b3 = (const float*)d_in[7];
    float* out = (float*)d_out;

    if (ws_size < WS_NEED) return;   // visible failure rather than corruption

    char* ws = (char*)d_ws;
    unsigned short* W1h = (unsigned short*)(ws + OFF_W1H);
    unsigned short* W1l = (unsigned short*)(ws + OFF_W1L);
    unsigned short* W2h = (unsigned short*)(ws + OFF_W2H);
    unsigned short* W2l = (unsigned short*)(ws + OFF_W2L);
    unsigned short* W3h = (unsigned short*)(ws + OFF_W3H);
    unsigned short* W3l = (unsigned short*)(ws + OFF_W3L);
    float*          P1  = (float*)(ws + OFF_P1);
    float*          P2  = (float*)(ws + OFF_P2);
    float*          P3  = (float*)(ws + OFF_P3);
    const size_t PS = (size_t)4096 * 1024;   // fp32 plane stride (elements)

    // Weight converts (every launch — same work per call, graph-safe).
    convert_w_t<<<dim3(1024 / 64, 12544 / 64), 256, 0, stream>>>(w1, W1h, W1l, 12544, 1024);
    convert_w_t<<<dim3(1024 / 64, 1024  / 64), 256, 0, stream>>>(w2, W2h, W2l, 1024, 1024);
    convert_w_t<<<dim3(384  / 64, 1024  / 64), 256, 0, stream>>>(w3, W3h, W3l, 1024, 324);

    // L1: X[4096,12544] @ W1 -> P1[2][4096][1024]  (split-K=2)
    gemm3split<0><<<dim3(4096 / BM, 1024 / BN, 2), 256, 0, stream>>>(
        features, nullptr, nullptr, W1h, W1l, P1, 12544, 98, 1024);

    // L2: relu(P1.sum + b1) @ W2 -> P2[2][4096][1024]  (fused A, split-K=2)
    gemm3split<1><<<dim3(4096 / BM, 1024 / BN, 2), 256, 0, stream>>>(
        P1, P1 + PS, b1, W2h, W2l, P2, 1024, 8, 1024);

    // L3: relu(P2.sum + b2) @ W3 -> P3[4][4096][384]  (fused A, split-K=4)
    gemm3split<1><<<dim3(4096 / BM, 384 / BN, 4), 256, 0, stream>>>(
        P2, P2 + PS, b2, W3h, W3l, P3, 1024, 4, 384);

    // Final: sum P3 + b3, crop 384 -> 324.
    reduce_bias_out<<<dim3(3, 4096), 128, 0, stream>>>(P3, b3, out);
}

// Round 13
// 541.520 us; speedup vs baseline: 2.9034x; 1.1554x over previous
//
#include <hip/hip_runtime.h>

// ROIBBoxHead: out = relu(relu(X@W1+b1)@W2+b2)@W3+b3
// X=[4096,12544] fp32, W1=[12544,1024], W2=[1024,1024], W3=[1024,324].
// R12/R13: 2-pass SPLIT-FP16 emulated-fp32 GEMM on the MFMA pipe:
//   a*b ~= (ah+al)*bh,  ah,al = fp16 split of a (exact to 2^-22),
//   bh = fp16(b) (RTN, rel err 2^-12).
//   Per-layer error ~2e-4 rms -> final absmax ~2.5e-3, well under the
//   passing 0.0156. (bf16 2-pass would be ~2e-2 -> must be fp16.)
// Rationale: R11 counters show GEMM1 is LDS-read-BW bound (32KB reads /
// 96 MFMA per K-tile per wave caps MfmaUtil at ~45%; measured 41.5%).
// 2-pass cuts MFMA FLOPs 33% and LDS reads 25% (sBl deleted, LDS=48KB).
// 128x128 tile, BK=64, 4 waves, mfma_f32_16x16x32_f16, XOR swizzle (r&7).
// Fused dataflow (R7-proven): GEMMs write fp32 split-K partials; next
// GEMM's A-staging does reduce+bias+relu+split on the fly.

typedef __attribute__((ext_vector_type(4)))  float          f32x4;
typedef __attribute__((ext_vector_type(8)))  _Float16       f16x8;
typedef __attribute__((ext_vector_type(4)))  _Float16       f16x4;
typedef __attribute__((ext_vector_type(4)))  unsigned int   uint4v;

#define BM 128
#define BN 128
#define BK 64

// fp16 split: x ~= h + l, |x - h - l| <= ~2^-22 |x|.
__device__ __forceinline__ void split_f16(float x, _Float16& h, _Float16& l) {
    h = (_Float16)x;                  // RTN
    l = (_Float16)(x - (float)h);     // residual, fp16 exact to 2^-11 of itself
}

// ---------------------------------------------------------------------------
// Weight conversion: W[K][N] fp32 -> WhT[Npad][K] fp16 (transposed).
// 64x64 LDS transpose tile; vectorized f16x8 stores along K.
// grid = (Npad/64, K/64), block = 256. Rows n in [N,Npad) zero-filled.
// ---------------------------------------------------------------------------
__global__ __launch_bounds__(256) void convert_w_t(const float* __restrict__ W,
                                                   _Float16* __restrict__ WhT,
                                                   int K, int N) {
    __shared__ float tile[64][65];
    const int k0 = blockIdx.y * 64;
    const int n0 = blockIdx.x * 64;
    const int tid = threadIdx.x;
    const int kr = tid >> 4;          // 0..15
    const int nc = (tid & 15) * 4;    // 0..60
#pragma unroll
    for (int i = 0; i < 4; ++i) {
        const int k = kr + 16 * i;
        f32x4 v = (f32x4){0.f, 0.f, 0.f, 0.f};
        if (n0 + nc < N) v = *(const f32x4*)(W + (size_t)(k0 + k) * N + n0 + nc);
        tile[k][nc + 0] = v[0];
        tile[k][nc + 1] = v[1];
        tile[k][nc + 2] = v[2];
        tile[k][nc + 3] = v[3];
    }
    __syncthreads();
    const int nr = tid >> 2;          // 0..63
    const int kc = (tid & 3) * 16;    // 0..48
    f16x8 h0, h1;
#pragma unroll
    for (int j = 0; j < 8; ++j) {
        h0[j] = (_Float16)tile[kc + j][nr];
        h1[j] = (_Float16)tile[kc + 8 + j][nr];
    }
    const size_t o = (size_t)(n0 + nr) * K + k0 + kc;
    *(f16x8*)(WhT + o)     = h0;
    *(f16x8*)(WhT + o + 8) = h1;
}

// ---------------------------------------------------------------------------
// Split-fp16 GEMM: Cpartial[z] = A @ B (K-slice per blockIdx.z), BK=64.
//   ASRC=0: A = fp32 matrix (X), fp16 hi/lo split during staging.
//   ASRC=1: A = relu(P0[off] + P1[off] + abias[k]) computed during staging
//           (fuses the previous layer's split-K reduce + bias + relu).
// Output: raw fp32 partial to Cf + z*gridDim.x*BM*ldC (N padded, no guard).
// Inner: mfma_f32_16x16x32_f16, 2 MFMA per (m,n) per kk (ah*bh + al*bh).
// LDS = sAh+sAl+sBh = 48KB, XOR swizzle (r&7) -> conflict-free (R2-proven
// byte addressing, identical to the bf16 layout that measured 0 conflicts).
// ---------------------------------------------------------------------------
template<int ASRC>
__global__ __launch_bounds__(256, 2)
void gemm3split(const float* __restrict__ A0,
                const float* __restrict__ A1,
                const float* __restrict__ abias,
                const _Float16* __restrict__ BhT,
                float* __restrict__ Cf,
                int K, int ktiles, int ldC) {
    const int tid  = threadIdx.x;
    const int lane = tid & 63;
    const int wave = tid >> 6;
    const int kgrp = lane >> 4;
    const int m0 = blockIdx.x * BM;
    const int n0 = blockIdx.y * BN;
    const int kt_base = blockIdx.z * ktiles;
    const int wm = (wave >> 1) * 64;
    const int wn = (wave & 1) * 64;

    __shared__ __align__(16) _Float16 sAh[BM * BK];
    __shared__ __align__(16) _Float16 sAl[BM * BK];
    __shared__ __align__(16) _Float16 sBh[BN * BK];

    f32x4 acc[4][4];
#pragma unroll
    for (int m = 0; m < 4; ++m)
#pragma unroll
        for (int n = 0; n < 4; ++n) acc[m][n] = (f32x4){0.f, 0.f, 0.f, 0.f};

    const int arow   = tid >> 4;   // A staging: 16 rows x 16 chunks(4 floats)
    const int acol4  = tid & 15;
    const int brow   = tid >> 3;   // B staging: 32 rows x 8 chunks(8 fp16)
    const int bchunk = tid & 7;

    f32x4  aF[8];                  // plane-0 (or X)
    f32x4  aG[8];                  // plane-1 (ASRC=1 only)
    f32x4  aB;                     // bias chunk (ASRC=1 only)
    uint4v bH[4];

    auto load_tile = [&](int kt) {
        const int k0 = (kt_base + kt) * BK;
#pragma unroll
        for (int i = 0; i < 8; ++i) {
            const size_t off = (size_t)(m0 + arow + 16 * i) * K + k0 + acol4 * 4;
            aF[i] = *(const f32x4*)(A0 + off);
            if constexpr (ASRC == 1) aG[i] = *(const f32x4*)(A1 + off);
        }
        if constexpr (ASRC == 1) aB = *(const f32x4*)(abias + k0 + acol4 * 4);
#pragma unroll
        for (int i = 0; i < 4; ++i) {
            const size_t off = (size_t)(n0 + brow + 32 * i) * K + k0 + bchunk * 8;
            bH[i] = *(const uint4v*)(BhT + off);
        }
    };

    auto stage_to_lds = [&]() {
#pragma unroll
        for (int i = 0; i < 8; ++i) {
            const int r = arow + 16 * i;
            f16x4 h, l;
#pragma unroll
            for (int j = 0; j < 4; ++j) {
                float v = aF[i][j];
                if constexpr (ASRC == 1) v = fmaxf(v + aG[i][j] + aB[j], 0.0f);
                _Float16 hh, ll;
                split_f16(v, hh, ll);
                h[j] = hh; l[j] = ll;
            }
            const int ck  = acol4 >> 1;
            const int sub = (acol4 & 1) * 4;
            const int off = r * BK + ((ck ^ (r & 7)) << 3) + sub;
            *(f16x4*)(sAh + off) = h;
            *(f16x4*)(sAl + off) = l;
        }
#pragma unroll
        for (int i = 0; i < 4; ++i) {
            const int r   = brow + 32 * i;
            const int off = r * BK + ((bchunk ^ (r & 7)) << 3);
            *(uint4v*)(sBh + off) = bH[i];
        }
    };

    load_tile(0);

    for (int kt = 0; kt < ktiles; ++kt) {
        __syncthreads();                 // prev compute done
        stage_to_lds();
        __syncthreads();                 // LDS ready
        if (kt + 1 < ktiles) load_tile(kt + 1);  // in flight across compute
#pragma unroll
        for (int kk = 0; kk < BK / 32; ++kk) {
            const int ck = kk * 4 + kgrp;
            f16x8 fah[4], fal[4];
#pragma unroll
            for (int m = 0; m < 4; ++m) {
                const int r   = wm + m * 16 + (lane & 15);
                const int off = r * BK + ((ck ^ (r & 7)) << 3);
                fah[m] = *(const f16x8*)(sAh + off);
                fal[m] = *(const f16x8*)(sAl + off);
            }
#pragma unroll
            for (int n = 0; n < 4; ++n) {
                const int r   = wn + n * 16 + (lane & 15);
                const int off = r * BK + ((ck ^ (r & 7)) << 3);
                const f16x8 fbh = *(const f16x8*)(sBh + off);
#pragma unroll
                for (int m = 0; m < 4; ++m) {
                    acc[m][n] = __builtin_amdgcn_mfma_f32_16x16x32_f16(fah[m], fbh, acc[m][n], 0, 0, 0);
                    acc[m][n] = __builtin_amdgcn_mfma_f32_16x16x32_f16(fal[m], fbh, acc[m][n], 0, 0, 0);
                }
            }
        }
    }

    // Epilogue: raw fp32 partial. C/D layout (verified):
    // col = lane&15, row = (lane>>4)*4 + reg.
    const int col  = lane & 15;
    const int row4 = (lane >> 4) * 4;
    float* Cp = Cf + (size_t)blockIdx.z * (size_t)gridDim.x * BM * ldC;
#pragma unroll
    for (int n = 0; n < 4; ++n) {
        const int gn = n0 + wn + n * 16 + col;
#pragma unroll
        for (int m = 0; m < 4; ++m) {
            const int gmb = m0 + wm + m * 16 + row4;
#pragma unroll
            for (int j = 0; j < 4; ++j) {
                Cp[(size_t)(gmb + j) * ldC + gn] = acc[m][n][j];
            }
        }
    }
}

// ---------------------------------------------------------------------------
// Final: sum 4 partials [4][4096][384] + bias, crop N 384->324.
// grid = (3, 4096), block = 128.
// ---------------------------------------------------------------------------
__global__ __launch_bounds__(128) void reduce_bias_out(
        const float* __restrict__ P, const float* __restrict__ bias,
        float* __restrict__ out) {
    const int col = blockIdx.x * 128 + threadIdx.x;   // 0..383
    const int row = blockIdx.y;
    if (col >= 324) return;
    float s = bias[col];
#pragma unroll
    for (int z = 0; z < 4; ++z)
        s += P[((size_t)z * 4096 + row) * 384 + col];
    out[(size_t)row * 324 + col] = s;
}

// ---------------------------------------------------------------------------
// Workspace layout (bytes). Total = 95,682,560 (< 124,256,256 proven by R3).
//   W1h fp16 [0 .. 25,690,112)
//   W2h fp16 [25,690,112 .. 27,787,264)
//   W3h fp16 [27,787,264 .. 28,573,696)   (Npad=384, zero-filled 324..383)
//   P1 (2 fp32 planes) [28,573,696 .. 62,128,128)   GEMM1 out / GEMM2 in
//   P2 (2 fp32 planes) [62,128,128 .. 95,682,560)   GEMM2 out / GEMM3 in
//   P3 (4x4096x384 f32 = 25,165,824) aliases P1 (dead by GEMM3).
// ---------------------------------------------------------------------------
static constexpr size_t SZ_W1P   = (size_t)1024 * 12544 * 2;   // 25,690,112
static constexpr size_t SZ_W2P   = (size_t)1024 * 1024  * 2;   //  2,097,152
static constexpr size_t SZ_W3P   = (size_t)384  * 1024  * 2;   //    786,432
static constexpr size_t SZ_PLANE = (size_t)4096 * 1024 * 4;    // 16,777,216
static constexpr size_t OFF_W1   = 0;
static constexpr size_t OFF_W2   = OFF_W1 + SZ_W1P;
static constexpr size_t OFF_W3   = OFF_W2 + SZ_W2P;
static constexpr size_t OFF_P1   = OFF_W3 + SZ_W3P;            // 28,573,696
static constexpr size_t OFF_P2   = OFF_P1 + 2 * SZ_PLANE;      // 62,128,128
static constexpr size_t WS_NEED  = OFF_P2 + 2 * SZ_PLANE;      // 95,682,560
static constexpr size_t OFF_P3   = OFF_P1;                     // alias P1

extern "C" void kernel_launch(void* const* d_in, const int* in_sizes, int n_in,
                              void* d_out, int out_size, void* d_ws, size_t ws_size,
                              hipStream_t stream) {
    const float* features = (const float*)d_in[0];
    // d_in[1] = batch_indices: mathematically dead (permutation cancels).
    const float* w1 = (const float*)d_in[2];
    const float* b1 = (const float*)d_in[3];
    const float* w2 = (const float*)d_in[4];
    const float* b2 = (const float*)d_in[5];
    const float* w3 = (const float*)d_in[6];
    const float* b3 = (const float*)d_in[7];
    float* out = (float*)d_out;

    if (ws_size < WS_NEED) return;   // visible failure rather than corruption

    char* ws = (char*)d_ws;
    _Float16* W1h = (_Float16*)(ws + OFF_W1);
    _Float16* W2h = (_Float16*)(ws + OFF_W2);
    _Float16* W3h = (_Float16*)(ws + OFF_W3);
    float*    P1  = (float*)(ws + OFF_P1);
    float*    P2  = (float*)(ws + OFF_P2);
    float*    P3  = (float*)(ws + OFF_P3);
    const size_t PS = (size_t)4096 * 1024;   // fp32 plane stride (elements)

    // Weight converts (every launch — same work per call, graph-safe).
    convert_w_t<<<dim3(1024 / 64, 12544 / 64), 256, 0, stream>>>(w1, W1h, 12544, 1024);
    convert_w_t<<<dim3(1024 / 64, 1024  / 64), 256, 0, stream>>>(w2, W2h, 1024, 1024);
    convert_w_t<<<dim3(384  / 64, 1024  / 64), 256, 0, stream>>>(w3, W3h, 1024, 324);

    // L1: X[4096,12544] @ W1 -> P1[2][4096][1024]  (split-K=2)
    gemm3split<0><<<dim3(4096 / BM, 1024 / BN, 2), 256, 0, stream>>>(
        features, nullptr, nullptr, W1h, P1, 12544, 98, 1024);

    // L2: relu(P1.sum + b1) @ W2 -> P2[2][4096][1024]  (fused A, split-K=2)
    gemm3split<1><<<dim3(4096 / BM, 1024 / BN, 2), 256, 0, stream>>>(
        P1, P1 + PS, b1, W2h, P2, 1024, 8, 1024);

    // L3: relu(P2.sum + b2) @ W3 -> P3[4][4096][384]  (fused A, split-K=4)
    gemm3split<1><<<dim3(4096 / BM, 384 / BN, 4), 256, 0, stream>>>(
        P2, P2 + PS, b2, W3h, P3, 1024, 4, 384);

    // Final: sum P3 + b3, crop 384 -> 324.
    reduce_bias_out<<<dim3(3, 4096), 128, 0, stream>>>(P3, b3, out);
}